// Round 8
// baseline (197.912 us; speedup 1.0000x reference)
//
#include <hip/hip_runtime.h>

// Problem constants (N,C,H,W) = (8,19,384,384)
#define NCLS 19
#define HW   147456            // 384*384
#define MPIX 1179648           // 8*384*384
#define NB   256               // histogram buckets per class (LDS-resident)
#define TPB  384               // 6 waves/block
#define NBLK 1536              // 1536*384*2 == MPIX
#define HSZ  (NCLS * NB)       // 4864 histogram words per block
#define NREP 32                // global histogram replicas (kills atomic hot-word chains)

// Kernel A: 2 px/thread float2, r6/r7 shape (30 waves/CU), ONE load per
// element enforced. Key finding (r1..r7): VGPR_Count was always < the 38-76
// needed for v[NCLS] residency -> the compiler silently re-loaded logits from
// cache in up to 3 passes (max/exp/p). All configs pinned A at ~65us with
// every pipe <35% busy = serialized cache-latency sweeps. The empty inline-asm
// "+v" pins below make each loaded (and exp'd) value opaque so the compiler
// CANNOT rematerialize-by-reload: true 1-load/1-exp/1-mul per element.
// hist[c][k] packs cnt low 16 / pos high 16 (block covers 768 px < 65536).
// Flush: skip-zero u64 atomics into replica (b & 31) - r7-proven.
__global__ void __launch_bounds__(TPB, 8) softmax_err_hist(
    const float* __restrict__ logits,
    const int* __restrict__ label,
    float* __restrict__ errs,                      // [C, M]
    unsigned long long* __restrict__ hist64)       // [NREP][HSZ] cnt|pos packed
{
    __shared__ unsigned int hist[HSZ];
    const int tid = threadIdx.x;
    const int b = blockIdx.x;

    for (int i = tid; i < HSZ; i += TPB) hist[i] = 0u;
    __syncthreads();

    const int m = (b * TPB + tid) * 2;        // 2 consecutive pixels, same image
    const int n = m / HW;                     // HW % 2 == 0 -> both px same n
    const int base = m + n * (NCLS - 1) * HW; // float2-aligned (m % 2 == 0)

    const int2 lbl = *(const int2*)(label + m);

    float2 v[NCLS];
    float2 mx = make_float2(-1e30f, -1e30f);
#pragma unroll
    for (int c = 0; c < NCLS; ++c) {
        float2 x = *(const float2*)(logits + base + c * HW);
        // pin the loaded value: compiler may not re-load it later
        asm volatile("" : "+v"(x.x), "+v"(x.y));
        v[c] = x;
        mx.x = fmaxf(mx.x, x.x);
        mx.y = fmaxf(mx.y, x.y);
    }
    float2 s = make_float2(0.f, 0.f);
#pragma unroll
    for (int c = 0; c < NCLS; ++c) {
        float2 e;
        e.x = __expf(v[c].x - mx.x);
        e.y = __expf(v[c].y - mx.y);
        // pin the exp result: may not be recomputed in the p-pass
        asm volatile("" : "+v"(e.x), "+v"(e.y));
        v[c] = e;
        s.x += e.x; s.y += e.y;
    }
    const float2 inv = make_float2(1.f / s.x, 1.f / s.y);

#pragma unroll
    for (int c = 0; c < NCLS; ++c) {
        float2 p;
        p.x = v[c].x * inv.x;
        p.y = v[c].y * inv.y;
        float2 err;
        err.x = (c == lbl.x) ? (1.0f - p.x) : p.x;
        err.y = (c == lbl.y) ? (1.0f - p.y) : p.y;
        *(float2*)(errs + (size_t)c * MPIX + m) = err;

        int k0 = min(max((int)(err.x * (float)NB), 0), NB - 1);
        int k1 = min(max((int)(err.y * (float)NB), 0), NB - 1);
        atomicAdd(&hist[c * NB + k0], 1u + ((c == lbl.x) ? 65536u : 0u));
        atomicAdd(&hist[c * NB + k1], 1u + ((c == lbl.y) ? 65536u : 0u));
    }
    __syncthreads();

    // skip-zero u64 atomic flush into this block's replica:
    // cnt (16b) -> low32, pos (16b) -> high32. ~27% of words nonzero.
    unsigned long long* dst = hist64 + (size_t)(b & (NREP - 1)) * HSZ;
    for (int i = tid; i < HSZ; i += TPB) {
        unsigned int w = hist[i];
        if (w) {
            unsigned long long add =
                (unsigned long long)(w & 0xFFFFu) |
                ((unsigned long long)(w >> 16) << 32);
            atomicAdd(&dst[i], add);
        }
    }
}

__device__ __forceinline__ double jaccval(unsigned int n, unsigned int p, unsigned int npos)
{
    // J = 1 - (npos - p) / (npos + n - p); define 0/0 -> 0
    unsigned int denom = (npos - p) + n;
    if (denom == 0u) return 0.0;
    return 1.0 - (double)(npos - p) / (double)denom;
}

// Kernel B: one block per class; thread t owns bucket t.
// Reduces the 32 replicas (1.25 MB total), then suffix + trapezoid scan.
__global__ void __launch_bounds__(NB) lovasz_scan(
    const unsigned long long* __restrict__ hist64,  // [NREP][HSZ]
    float* __restrict__ out0)
{
    const int c = blockIdx.x;
    const int t = threadIdx.x;

    unsigned long long sum = 0ull;
#pragma unroll
    for (int r = 0; r < NREP; ++r)
        sum += hist64[(size_t)r * HSZ + c * NB + t];

    __shared__ unsigned int cntS[NB], posS[NB];
    cntS[t] = (unsigned int)(sum & 0xFFFFFFFFull);
    posS[t] = (unsigned int)(sum >> 32);
    __syncthreads();

    // suffix-exclusive counts (buckets above t) + total positives
    unsigned int N = 0, P = 0, totP = 0;
    for (int u = 0; u < NB; ++u) {
        totP += posS[u];
        if (u > t) { N += cntS[u]; P += posS[u]; }
    }

    double Jprev = jaccval(N, P, totP);
    N += cntS[t]; P += posS[t];
    double Jnew = jaccval(N, P, totP);
    double acc = 0.5 * (Jprev + Jnew);

    __shared__ double red[NB];
    red[t] = acc;
    __syncthreads();
    for (int s2 = NB / 2; s2 > 0; s2 >>= 1) {
        if (t < s2) red[t] += red[t + s2];
        __syncthreads();
    }
    if (t == 0) {
        double loss_c = red[0] / (double)NB;   // × bucket width
        atomicAdd(out0, (float)(loss_c / (double)NCLS));
    }
}

extern "C" void kernel_launch(void* const* d_in, const int* in_sizes, int n_in,
                              void* d_out, int out_size, void* d_ws, size_t ws_size,
                              hipStream_t stream)
{
    const float* logits = (const float*)d_in[0];
    const int*   label  = (const int*)d_in[1];
    float* out = (float*)d_out;

    // ws layout: [hist64 NREP*HSZ u64] = 1.25 MB
    unsigned long long* hist64 = (unsigned long long*)d_ws;

    hipMemsetAsync(d_ws, 0, (size_t)NREP * HSZ * sizeof(unsigned long long), stream);
    hipMemsetAsync(d_out, 0, sizeof(float), stream);

    softmax_err_hist<<<NBLK, TPB, 0, stream>>>(logits, label, out + 1, hist64);
    lovasz_scan<<<NCLS, NB, 0, stream>>>(hist64, out);
}